// Round 7
// baseline (423.530 us; speedup 1.0000x reference)
//
#include <hip/hip_runtime.h>
#include <math.h>

// Problem constants (fixed by setup_inputs)
#define NODES_TOT 7424      // 64 * 116
#define EDGES     237568    // NODES_TOT * 32
#define BATCH     64
#define NN        116
#define KDIM      7424      // FC K dim
#define N1        7424      // FC1 out
#define N2        13456     // FC2 out (116*116)
#define SUPER     29        // KDIM / 256 super-steps
#define KSPLIT1   4
#define KSPLIT2   2

typedef __attribute__((ext_vector_type(8))) short bf16x8;
typedef __attribute__((ext_vector_type(4))) float f32x4;
typedef __attribute__((ext_vector_type(4))) short s16x4;

__device__ __forceinline__ float mish_f(float v) {
    float sp = fmaxf(v, 0.0f) + log1pf(expf(-fabsf(v)));
    return v * tanhf(sp);
}

__device__ __forceinline__ unsigned short bf_rne(float f) {
    unsigned u = __float_as_uint(f);
    u += 0x7fffu + ((u >> 16) & 1u);
    return (unsigned short)(u >> 16);
}

// ---------- small utility ----------
__global__ void zero_kernel(int* __restrict__ p, int n) {
    int i = blockIdx.x * 256 + threadIdx.x;
    if (i < n) p[i] = 0;
}

// ---------- CSR build ----------
__global__ void hist_kernel(const int* __restrict__ dst, int* __restrict__ hist) {
    int e = blockIdx.x * 256 + threadIdx.x;
    if (e < EDGES) atomicAdd(&hist[dst[e]], 1);
}

__global__ void scan_kernel(const int* __restrict__ hist, int* __restrict__ row_start,
                            int* __restrict__ cursor) {
    __shared__ int s[1024];
    int t = threadIdx.x;
    int base = t * 8;
    int loc[8];
    int sum = 0;
    #pragma unroll
    for (int c = 0; c < 8; ++c) {
        int idx = base + c;
        int v = (idx < NODES_TOT) ? hist[idx] : 0;
        loc[c] = sum;
        sum += v;
    }
    s[t] = sum;
    __syncthreads();
    for (int off = 1; off < 1024; off <<= 1) {
        int v = (t >= off) ? s[t - off] : 0;
        __syncthreads();
        s[t] += v;
        __syncthreads();
    }
    int excl = s[t] - sum;
    #pragma unroll
    for (int c = 0; c < 8; ++c) {
        int idx = base + c;
        if (idx < NODES_TOT) {
            int r = excl + loc[c];
            row_start[idx] = r;
            cursor[idx] = r;
        }
    }
}

__global__ void csr_fill_kernel(const int* __restrict__ src, const int* __restrict__ dst,
                                int* __restrict__ cursor, int* __restrict__ csr_src) {
    int e = blockIdx.x * 256 + threadIdx.x;
    if (e < EDGES) {
        int p = atomicAdd(&cursor[dst[e]], 1);
        csr_src[p] = src[e];
    }
}

// ---------- fused mean-aggregate + SAGE linear + mish ----------
template <bool BF>
__global__ void __launch_bounds__(256) conv_kernel(
        const float* __restrict__ x, const int* __restrict__ csr_src,
        const int* __restrict__ row_start, const int* __restrict__ deg_arr,
        const float* __restrict__ w_l, const float* __restrict__ b_l,
        const float* __restrict__ w_r, void* __restrict__ h_out_v) {
    __shared__ float wlT[64 * 64];   // [k][f]
    __shared__ float wrT[64 * 64];   // [k][f]
    __shared__ float mv[4][64];
    __shared__ float xv[4][64];
    int t = threadIdx.x;
    for (int i = 0; i < 16; ++i) {
        int idx = t + i * 256;
        int f = idx >> 6, k = idx & 63;
        wlT[k * 64 + f] = w_l[idx];
        wrT[k * 64 + f] = w_r[idx];
    }
    int g = t >> 6, f = t & 63;
    __syncthreads();
    for (int nb = blockIdx.x * 4; nb < NODES_TOT; nb += gridDim.x * 4) {
        int node = nb + g;
        int deg = deg_arr[node];
        int rs = row_start[node];
        float sum = 0.f;
        for (int e = 0; e < deg; ++e) {
            int s = csr_src[rs + e];
            sum += x[s * 64 + f];
        }
        float mean = sum / (float)max(deg, 1);
        mv[g][f] = mean;
        xv[g][f] = x[node * 64 + f];
        __syncthreads();
        float o = b_l[f];
        #pragma unroll
        for (int k = 0; k < 64; ++k) {
            o = fmaf(mv[g][k], wlT[k * 64 + f], o);
            o = fmaf(xv[g][k], wrT[k * 64 + f], o);
        }
        float m = mish_f(o);
        if (BF) ((unsigned short*)h_out_v)[node * 64 + f] = bf_rne(m);
        else    ((float*)h_out_v)[node * 64 + f] = m;
        __syncthreads();
    }
}

// ---------- big-burst bf16-MFMA GEMM: Cp[by][64][N] = A[64][Ksl] * W[Ntile][Ksl]^T ---
// BK=256: each block-step reads 1 KB contiguous per W row (DRAM activation-friendly).
// W reg-staged fp32 -> bf16 -> LDS chunk layout [octet o(0..31)][row(0..63)][8 bf16]
// (uniform-optimal bank use on both ds_write_b64 and ds_read_b128). A fragments read
// directly from global (L2-resident), 1-deep register prefetch in the kk loop.
// One raw lgkmcnt(0)+s_barrier per super-step; W(s+1) register loads are issued
// before the MFMA phase so HBM latency hides under ~2000+ cycles of compute.
template <int KS>
__global__ void __launch_bounds__(256, 2) gemm_big(
        const unsigned short* __restrict__ Abf, const float* __restrict__ W,
        float* __restrict__ Cp, int N) {
    __shared__ __align__(16) unsigned short Wlds[2][16384];   // 2 x 32 KB
    int t = threadIdx.x;
    int bx = blockIdx.x, by = blockIdx.y;
    int sb0 = (by * SUPER) / KS;
    int sb1 = ((by + 1) * SUPER) / KS;
    int S = sb1 - sb0;
    int n0 = bx * 64;
    // staging: row r = t>>2, quad q = t&3; instr j: 4 lanes cover 64B contiguous
    int r = t >> 2, q = t & 3;
    int wr = n0 + r; if (wr >= N) wr = N - 1;
    const float* wsrc = W + (size_t)wr * KDIM + (size_t)sb0 * 256 + q * 4;
    // compute lanes
    int wv = t >> 6, l = t & 63, l15 = l & 15, hi = l >> 4;
    const unsigned short* arow[4];
    #pragma unroll
    for (int g = 0; g < 4; ++g)
        arow[g] = Abf + (size_t)(g * 16 + l15) * KDIM + (size_t)sb0 * 256 + hi * 8;

    f32x4 acc[4];
    #pragma unroll
    for (int g = 0; g < 4; ++g) acc[g] = (f32x4){0.f, 0.f, 0.f, 0.f};

    f32x4 w[16];

#define LOADW(s) do {                                                      \
        size_t ko = (size_t)(s) * 256;                                     \
        _Pragma("unroll")                                                  \
        for (int j = 0; j < 16; ++j)                                       \
            w[j] = *(const f32x4*)(wsrc + ko + j * 16);                    \
    } while (0)

    // thread's f32x4 j covers k [j*16+q*4, +4) -> octet o = 2j + (q>>1), half q&1
#define CONVW(nb) do {                                                     \
        _Pragma("unroll")                                                  \
        for (int j = 0; j < 16; ++j) {                                     \
            s16x4 cv;                                                      \
            _Pragma("unroll")                                              \
            for (int e = 0; e < 4; ++e) cv[e] = (short)bf_rne(w[j][e]);    \
            *(s16x4*)&Wlds[nb][((2 * j + (q >> 1)) * 64 + r) * 8 + (q & 1) * 4] = cv; \
        }                                                                  \
    } while (0)

#define MFMA_STEP(b, s) do {                                               \
        size_t ko = (size_t)(s) * 256;                                     \
        bf16x8 a0 = *(const bf16x8*)(arow[0] + ko);                        \
        bf16x8 a1 = *(const bf16x8*)(arow[1] + ko);                        \
        bf16x8 a2 = *(const bf16x8*)(arow[2] + ko);                        \
        bf16x8 a3 = *(const bf16x8*)(arow[3] + ko);                        \
        _Pragma("unroll")                                                  \
        for (int kk = 0; kk < 8; ++kk) {                                   \
            bf16x8 n0_, n1_, n2_, n3_;                                     \
            if (kk < 7) {                                                  \
                n0_ = *(const bf16x8*)(arow[0] + ko + (kk + 1) * 32);      \
                n1_ = *(const bf16x8*)(arow[1] + ko + (kk + 1) * 32);      \
                n2_ = *(const bf16x8*)(arow[2] + ko + (kk + 1) * 32);      \
                n3_ = *(const bf16x8*)(arow[3] + ko + (kk + 1) * 32);      \
            }                                                              \
            bf16x8 bh = *(const bf16x8*)&Wlds[b][((kk * 4 + hi) * 64 + wv * 16 + l15) * 8]; \
            acc[0] = __builtin_amdgcn_mfma_f32_16x16x32_bf16(a0, bh, acc[0], 0, 0, 0); \
            acc[1] = __builtin_amdgcn_mfma_f32_16x16x32_bf16(a1, bh, acc[1], 0, 0, 0); \
            acc[2] = __builtin_amdgcn_mfma_f32_16x16x32_bf16(a2, bh, acc[2], 0, 0, 0); \
            acc[3] = __builtin_amdgcn_mfma_f32_16x16x32_bf16(a3, bh, acc[3], 0, 0, 0); \
            if (kk < 7) { a0 = n0_; a1 = n1_; a2 = n2_; a3 = n3_; }        \
        }                                                                  \
    } while (0)

#define LBAR() asm volatile("s_waitcnt lgkmcnt(0)\n\ts_barrier" ::: "memory")

    // prologue
    LOADW(0);
    CONVW(0);
    LBAR();
    for (int s = 0; s < S; ++s) {
        int b = s & 1;
        if (s + 1 < S) LOADW(s + 1);
        MFMA_STEP(b, s);
        if (s + 1 < S) {
            CONVW(b ^ 1);
            LBAR();
        }
    }

#undef LOADW
#undef CONVW
#undef MFMA_STEP
#undef LBAR

    // store partials
    int gn = n0 + wv * 16 + l15;
    if (gn < N) {
        float* cp = Cp + (size_t)by * 64 * N;
        #pragma unroll
        for (int g = 0; g < 4; ++g)
            #pragma unroll
            for (int rr = 0; rr < 4; ++rr)
                cp[(size_t)(g * 16 + hi * 4 + rr) * N + gn] = acc[g][rr];
    }
}

// ---------- reduce partials + bias + mish + bf16 cast (FC1 epilogue) ----------
__global__ void reduce1_kernel(const float* __restrict__ Cp, const float* __restrict__ b,
                               unsigned short* __restrict__ A2) {
    int i4 = (blockIdx.x * 256 + threadIdx.x) * 4;
    if (i4 >= BATCH * N1) return;
    int n = i4 % N1;
    f32x4 acc = *(const f32x4*)(b + n);
    #pragma unroll
    for (int s = 0; s < KSPLIT1; ++s)
        acc += *(const f32x4*)(Cp + (size_t)s * BATCH * N1 + i4);
    s16x4 o;
    #pragma unroll
    for (int j = 0; j < 4; ++j) o[j] = (short)bf_rne(mish_f(acc[j]));
    *(s16x4*)(A2 + i4) = o;
}

// ---------- reduce partials + bias (FC2 epilogue) ----------
__global__ void reduce2_kernel(const float* __restrict__ Cp, const float* __restrict__ b,
                               float* __restrict__ C2) {
    int i4 = (blockIdx.x * 256 + threadIdx.x) * 4;
    if (i4 >= BATCH * N2) return;
    int n = i4 % N2;
    f32x4 acc = *(const f32x4*)(b + n);
    #pragma unroll
    for (int s = 0; s < KSPLIT2; ++s)
        acc += *(const f32x4*)(Cp + (size_t)s * BATCH * N2 + i4);
    *(f32x4*)(C2 + i4) = acc;
}

// ---------- symmetrize + unit diagonal (C2 L2-resident, bias pre-added) ----------
__global__ void sym_kernel(const float* __restrict__ C2, float* __restrict__ out) {
    int tid = blockIdx.x * 256 + threadIdx.x;
    if (tid >= BATCH * NN * NN) return;
    int j = tid % NN;
    int r = tid / NN;
    int i = r % NN;
    int b = r / NN;
    float v;
    if (i == j) {
        v = 1.0f;
    } else {
        v = 0.5f * (C2[(size_t)b * N2 + i * NN + j] + C2[(size_t)b * N2 + j * NN + i]);
    }
    out[tid] = v;
}

extern "C" void kernel_launch(void* const* d_in, const int* in_sizes, int n_in,
                              void* d_out, int out_size, void* d_ws, size_t ws_size,
                              hipStream_t stream) {
    const float* z     = (const float*)d_in[0];
    const int*   edge  = (const int*)d_in[1];
    const float* w1_l  = (const float*)d_in[3];
    const float* b1_l  = (const float*)d_in[4];
    const float* w1_r  = (const float*)d_in[5];
    const float* w2_l  = (const float*)d_in[6];
    const float* b2_l  = (const float*)d_in[7];
    const float* w2_r  = (const float*)d_in[8];
    const float* fc1_w = (const float*)d_in[9];
    const float* fc1_b = (const float*)d_in[10];
    const float* fc2_w = (const float*)d_in[11];
    const float* fc2_b = (const float*)d_in[12];
    float* out = (float*)d_out;

    char* ws = (char*)d_ws;
    size_t off = 0;
    auto alloc = [&](size_t bytes) {
        void* p = ws + off;
        off = (off + bytes + 255) & ~(size_t)255;
        return p;
    };
    int*            hist      = (int*)alloc(NODES_TOT * 4);
    int*            row_start = (int*)alloc(NODES_TOT * 4);
    int*            cursor    = (int*)alloc(NODES_TOT * 4);
    int*            csr_src   = (int*)alloc((size_t)EDGES * 4);
    float*          h1        = (float*)alloc((size_t)NODES_TOT * 64 * 4);
    unsigned short* A1        = (unsigned short*)alloc((size_t)NODES_TOT * 64 * 2);
    float*          Cp1       = (float*)alloc((size_t)KSPLIT1 * BATCH * N1 * 4);
    unsigned short* A2        = (unsigned short*)alloc((size_t)BATCH * N1 * 2);
    float*          Cp2       = (float*)alloc((size_t)KSPLIT2 * BATCH * N2 * 4);
    float*          C2        = (float*)alloc((size_t)BATCH * N2 * 4);

    const int* src = edge;
    const int* dst = edge + EDGES;

    zero_kernel<<<(NODES_TOT + 255) / 256, 256, 0, stream>>>(hist, NODES_TOT);
    hist_kernel<<<(EDGES + 255) / 256, 256, 0, stream>>>(dst, hist);
    scan_kernel<<<1, 1024, 0, stream>>>(hist, row_start, cursor);
    csr_fill_kernel<<<(EDGES + 255) / 256, 256, 0, stream>>>(src, dst, cursor, csr_src);

    conv_kernel<false><<<928, 256, 0, stream>>>(z, csr_src, row_start, hist, w1_l, b1_l, w1_r, h1);
    conv_kernel<true><<<928, 256, 0, stream>>>(h1, csr_src, row_start, hist, w2_l, b2_l, w2_r, A1);

    // FC1: partials over 4 k-splits, then fused reduce+bias+mish+cast
    gemm_big<KSPLIT1><<<dim3(N1 / 64, KSPLIT1), 256, 0, stream>>>(A1, fc1_w, Cp1, N1);
    reduce1_kernel<<<(BATCH * N1 / 4 + 255) / 256, 256, 0, stream>>>(Cp1, fc1_b, A2);

    // FC2: partials over 2 k-splits
    gemm_big<KSPLIT2><<<dim3((N2 + 63) / 64, KSPLIT2), 256, 0, stream>>>(A2, fc2_w, Cp2, N2);
    reduce2_kernel<<<(BATCH * N2 / 4 + 255) / 256, 256, 0, stream>>>(Cp2, fc2_b, C2);

    sym_kernel<<<(BATCH * NN * NN + 255) / 256, 256, 0, stream>>>(C2, out);
}

// Round 8
// 316.858 us; speedup vs baseline: 1.3367x; 1.3367x over previous
//
#include <hip/hip_runtime.h>
#include <math.h>

// Problem constants (fixed by setup_inputs)
#define NODES_TOT 7424      // 64 * 116
#define EDGES     237568    // NODES_TOT * 32
#define BATCH     64
#define NN        116
#define KDIM      7424      // FC K dim
#define N1        7424      // FC1 out
#define N2        13456     // FC2 out (116*116)
#define KSPLIT    4         // both GEMMs: 116 sub-steps / 4 = 29 per block

typedef __attribute__((ext_vector_type(8))) short bf16x8;
typedef __attribute__((ext_vector_type(4))) float f32x4;
typedef __attribute__((ext_vector_type(4))) short s16x4;

__device__ __forceinline__ float mish_f(float v) {
    float sp = fmaxf(v, 0.0f) + log1pf(expf(-fabsf(v)));
    return v * tanhf(sp);
}

__device__ __forceinline__ unsigned short bf_rne(float f) {
    unsigned u = __float_as_uint(f);
    u += 0x7fffu + ((u >> 16) & 1u);
    return (unsigned short)(u >> 16);
}

// ---------- small utility ----------
__global__ void zero_kernel(int* __restrict__ p, int n) {
    int i = blockIdx.x * 256 + threadIdx.x;
    if (i < n) p[i] = 0;
}

// ---------- CSR build ----------
__global__ void hist_kernel(const int* __restrict__ dst, int* __restrict__ hist) {
    int e = blockIdx.x * 256 + threadIdx.x;
    if (e < EDGES) atomicAdd(&hist[dst[e]], 1);
}

__global__ void scan_kernel(const int* __restrict__ hist, int* __restrict__ row_start,
                            int* __restrict__ cursor) {
    __shared__ int s[1024];
    int t = threadIdx.x;
    int base = t * 8;
    int loc[8];
    int sum = 0;
    #pragma unroll
    for (int c = 0; c < 8; ++c) {
        int idx = base + c;
        int v = (idx < NODES_TOT) ? hist[idx] : 0;
        loc[c] = sum;
        sum += v;
    }
    s[t] = sum;
    __syncthreads();
    for (int off = 1; off < 1024; off <<= 1) {
        int v = (t >= off) ? s[t - off] : 0;
        __syncthreads();
        s[t] += v;
        __syncthreads();
    }
    int excl = s[t] - sum;
    #pragma unroll
    for (int c = 0; c < 8; ++c) {
        int idx = base + c;
        if (idx < NODES_TOT) {
            int r = excl + loc[c];
            row_start[idx] = r;
            cursor[idx] = r;
        }
    }
}

__global__ void csr_fill_kernel(const int* __restrict__ src, const int* __restrict__ dst,
                                int* __restrict__ cursor, int* __restrict__ csr_src) {
    int e = blockIdx.x * 256 + threadIdx.x;
    if (e < EDGES) {
        int p = atomicAdd(&cursor[dst[e]], 1);
        csr_src[p] = src[e];
    }
}

// ---------- fused mean-aggregate + SAGE linear + mish ----------
template <bool BF>
__global__ void __launch_bounds__(256) conv_kernel(
        const float* __restrict__ x, const int* __restrict__ csr_src,
        const int* __restrict__ row_start, const int* __restrict__ deg_arr,
        const float* __restrict__ w_l, const float* __restrict__ b_l,
        const float* __restrict__ w_r, void* __restrict__ h_out_v) {
    __shared__ float wlT[64 * 64];   // [k][f]
    __shared__ float wrT[64 * 64];   // [k][f]
    __shared__ float mv[4][64];
    __shared__ float xv[4][64];
    int t = threadIdx.x;
    for (int i = 0; i < 16; ++i) {
        int idx = t + i * 256;
        int f = idx >> 6, k = idx & 63;
        wlT[k * 64 + f] = w_l[idx];
        wrT[k * 64 + f] = w_r[idx];
    }
    int g = t >> 6, f = t & 63;
    __syncthreads();
    for (int nb = blockIdx.x * 4; nb < NODES_TOT; nb += gridDim.x * 4) {
        int node = nb + g;
        int deg = deg_arr[node];
        int rs = row_start[node];
        float sum = 0.f;
        for (int e = 0; e < deg; ++e) {
            int s = csr_src[rs + e];
            sum += x[s * 64 + f];
        }
        float mean = sum / (float)max(deg, 1);
        mv[g][f] = mean;
        xv[g][f] = x[node * 64 + f];
        __syncthreads();
        float o = b_l[f];
        #pragma unroll
        for (int k = 0; k < 64; ++k) {
            o = fmaf(mv[g][k], wlT[k * 64 + f], o);
            o = fmaf(xv[g][k], wrT[k * 64 + f], o);
        }
        float m = mish_f(o);
        if (BF) ((unsigned short*)h_out_v)[node * 64 + f] = bf_rne(m);
        else    ((float*)h_out_v)[node * 64 + f] = m;
        __syncthreads();
    }
}

// ---------- burst-fetch bf16-MFMA GEMM (R5 structure + 512B W bursts) ----------
// Cp[by][64][N] = A[64][29*64] * W[Ntile][29*64]^T, sub-step BK=64, S=29 static.
// W fetched in 2-sub-step register bursts (8 x f32x4/thread = 512 B contiguous per
// W row per issue moment -> DRAM activation-friendly), two sets (wA/wB), 2-body
// flight. A staged reg->LDS as R5 (L2-resident, tiny DRAM share). LDS dbuf, raw
// lgkmcnt(0)+s_barrier per body, no vmcnt drains (compiler counts via reg deps).
__global__ void __launch_bounds__(256) gemm_burst(
        const unsigned short* __restrict__ Abf, const float* __restrict__ W,
        float* __restrict__ Cp, int N) {
    __shared__ __align__(16) short Wsh[2][4096];
    __shared__ __align__(16) short Ash[2][4096];
    int t = threadIdx.x;
    int bx = blockIdx.x, by = blockIdx.y;
    int n0 = bx * 64;
    // staging indices: row r = t>>2, quad q = t&3 (4 lanes cover one 64B line)
    int r = t >> 2, q = t & 3;
    int wr = n0 + r; if (wr >= N) wr = N - 1;
    const float*          wsrc = W   + (size_t)wr * KDIM + (size_t)by * 29 * 64 + q * 4;
    const unsigned short* asrc = Abf + (size_t)r  * KDIM + (size_t)by * 29 * 64 + q * 8;
    int fb = q >> 1, hf = q & 1;
    // compute indices
    int wv = t >> 6, l = t & 63, l15 = l & 15, hi = l >> 4;
    f32x4 acc[4];
    #pragma unroll
    for (int g = 0; g < 4; ++g) acc[g] = (f32x4){0.f, 0.f, 0.f, 0.f};

    f32x4 wA[8], wB[8];
    bf16x8 aEv[2], aOd[2];

#define IW2(dst, s) do {                                                  \
        dst[0] = *(const f32x4*)(wsrc + (s) * 64 + 0);                    \
        dst[1] = *(const f32x4*)(wsrc + (s) * 64 + 16);                   \
        dst[2] = *(const f32x4*)(wsrc + (s) * 64 + 32);                   \
        dst[3] = *(const f32x4*)(wsrc + (s) * 64 + 48);                   \
        dst[4] = *(const f32x4*)(wsrc + (s) * 64 + 64);                   \
        dst[5] = *(const f32x4*)(wsrc + (s) * 64 + 80);                   \
        dst[6] = *(const f32x4*)(wsrc + (s) * 64 + 96);                   \
        dst[7] = *(const f32x4*)(wsrc + (s) * 64 + 112);                  \
    } while (0)

#define IW1(dst, s) do {                                                  \
        dst[0] = *(const f32x4*)(wsrc + (s) * 64 + 0);                    \
        dst[1] = *(const f32x4*)(wsrc + (s) * 64 + 16);                   \
        dst[2] = *(const f32x4*)(wsrc + (s) * 64 + 32);                   \
        dst[3] = *(const f32x4*)(wsrc + (s) * 64 + 48);                   \
    } while (0)

#define IA(dst, s) do {                                                   \
        dst[0] = *(const bf16x8*)(asrc + (s) * 64);                       \
        dst[1] = *(const bf16x8*)(asrc + (s) * 64 + 32);                  \
    } while (0)

    // convert 4 f32x4 (one sub-step's W for this thread) + write W,A to LDS buf b
#define CW(W0, W1, W2, W3, av, b) do {                                    \
        s16x4 cv0, cv1, cv2, cv3;                                         \
        _Pragma("unroll")                                                 \
        for (int j = 0; j < 4; ++j) {                                     \
            cv0[j] = (short)bf_rne(W0[j]);                                \
            cv1[j] = (short)bf_rne(W1[j]);                                \
            cv2[j] = (short)bf_rne(W2[j]);                                \
            cv3[j] = (short)bf_rne(W3[j]);                                \
        }                                                                 \
        *(s16x4*)&Wsh[b][((0 + fb) * 64 + r) * 8 + hf * 4] = cv0;         \
        *(s16x4*)&Wsh[b][((2 + fb) * 64 + r) * 8 + hf * 4] = cv1;         \
        *(s16x4*)&Wsh[b][((4 + fb) * 64 + r) * 8 + hf * 4] = cv2;         \
        *(s16x4*)&Wsh[b][((6 + fb) * 64 + r) * 8 + hf * 4] = cv3;         \
        *(bf16x8*)&Ash[b][(q * 64 + r) * 8] = av[0];                      \
        *(bf16x8*)&Ash[b][((q + 4) * 64 + r) * 8] = av[1];                \
    } while (0)

#define MFMAPH(b) do {                                                    \
        _Pragma("unroll")                                                 \
        for (int s = 0; s < 2; ++s) {                                     \
            int fw = s * 4 + hi;                                          \
            bf16x8 bh = *(const bf16x8*)&Wsh[b][(fw * 64 + wv * 16 + l15) * 8]; \
            _Pragma("unroll")                                             \
            for (int g = 0; g < 4; ++g) {                                 \
                bf16x8 avv = *(const bf16x8*)&Ash[b][(fw * 64 + g * 16 + l15) * 8]; \
                acc[g] = __builtin_amdgcn_mfma_f32_16x16x32_bf16(avv, bh, acc[g], 0, 0, 0); \
            }                                                             \
        }                                                                 \
    } while (0)

#define LBAR() asm volatile("s_waitcnt lgkmcnt(0)\n\ts_barrier" ::: "memory")

    // prologue: wA={0,1}, wB={2,3}; A 2-deep
    IW2(wA, 0);
    IW2(wB, 2);
    IA(aEv, 0);
    IA(aOd, 1);
    CW(wA[0], wA[1], wA[2], wA[3], aEv, 0);    // sub 0 -> buf0
    LBAR();

    for (int g = 0; g < 7; ++g) {
        int kb = g * 4;
        // body kb+0 (buf0)
        MFMAPH(0);
        CW(wA[4], wA[5], wA[6], wA[7], aOd, 1);    // sub kb+1 -> buf1
        IA(aEv, kb + 2);
        LBAR();
        // body kb+1 (buf1)
        if (g < 6) IW2(wA, kb + 4); else IW1(wA, 28);
        MFMAPH(1);
        CW(wB[0], wB[1], wB[2], wB[3], aEv, 0);    // sub kb+2 -> buf0
        IA(aOd, kb + 3);
        LBAR();
        // body kb+2 (buf0)
        MFMAPH(0);
        CW(wB[4], wB[5], wB[6], wB[7], aOd, 1);    // sub kb+3 -> buf1
        IA(aEv, kb + 4);
        LBAR();
        // body kb+3 (buf1)
        if (g < 6) IW2(wB, kb + 6);
        MFMAPH(1);
        CW(wA[0], wA[1], wA[2], wA[3], aEv, 0);    // sub kb+4 -> buf0
        if (g < 6) IA(aOd, kb + 5);
        LBAR();
    }
    MFMAPH(0);                                      // sub 28 (buf0)

#undef IW2
#undef IW1
#undef IA
#undef CW
#undef MFMAPH
#undef LBAR

    // store partials
    int gn = n0 + wv * 16 + l15;
    if (gn < N) {
        float* cp = Cp + (size_t)by * 64 * N;
        #pragma unroll
        for (int g = 0; g < 4; ++g)
            #pragma unroll
            for (int rr = 0; rr < 4; ++rr)
                cp[(size_t)(g * 16 + hi * 4 + rr) * N + gn] = acc[g][rr];
    }
}

// ---------- reduce partials + bias + mish + bf16 cast (FC1 epilogue) ----------
__global__ void reduce1_kernel(const float* __restrict__ Cp, const float* __restrict__ b,
                               unsigned short* __restrict__ A2) {
    int i4 = (blockIdx.x * 256 + threadIdx.x) * 4;
    if (i4 >= BATCH * N1) return;
    int n = i4 % N1;
    f32x4 acc = *(const f32x4*)(b + n);
    #pragma unroll
    for (int s = 0; s < KSPLIT; ++s)
        acc += *(const f32x4*)(Cp + (size_t)s * BATCH * N1 + i4);
    s16x4 o;
    #pragma unroll
    for (int j = 0; j < 4; ++j) o[j] = (short)bf_rne(mish_f(acc[j]));
    *(s16x4*)(A2 + i4) = o;
}

// ---------- reduce partials + bias (FC2 epilogue) ----------
__global__ void reduce2_kernel(const float* __restrict__ Cp, const float* __restrict__ b,
                               float* __restrict__ C2) {
    int i4 = (blockIdx.x * 256 + threadIdx.x) * 4;
    if (i4 >= BATCH * N2) return;
    int n = i4 % N2;
    f32x4 acc = *(const f32x4*)(b + n);
    #pragma unroll
    for (int s = 0; s < KSPLIT; ++s)
        acc += *(const f32x4*)(Cp + (size_t)s * BATCH * N2 + i4);
    *(f32x4*)(C2 + i4) = acc;
}

// ---------- symmetrize + unit diagonal (C2 L2-resident, bias pre-added) ----------
__global__ void sym_kernel(const float* __restrict__ C2, float* __restrict__ out) {
    int tid = blockIdx.x * 256 + threadIdx.x;
    if (tid >= BATCH * NN * NN) return;
    int j = tid % NN;
    int r = tid / NN;
    int i = r % NN;
    int b = r / NN;
    float v;
    if (i == j) {
        v = 1.0f;
    } else {
        v = 0.5f * (C2[(size_t)b * N2 + i * NN + j] + C2[(size_t)b * N2 + j * NN + i]);
    }
    out[tid] = v;
}

extern "C" void kernel_launch(void* const* d_in, const int* in_sizes, int n_in,
                              void* d_out, int out_size, void* d_ws, size_t ws_size,
                              hipStream_t stream) {
    const float* z     = (const float*)d_in[0];
    const int*   edge  = (const int*)d_in[1];
    const float* w1_l  = (const float*)d_in[3];
    const float* b1_l  = (const float*)d_in[4];
    const float* w1_r  = (const float*)d_in[5];
    const float* w2_l  = (const float*)d_in[6];
    const float* b2_l  = (const float*)d_in[7];
    const float* w2_r  = (const float*)d_in[8];
    const float* fc1_w = (const float*)d_in[9];
    const float* fc1_b = (const float*)d_in[10];
    const float* fc2_w = (const float*)d_in[11];
    const float* fc2_b = (const float*)d_in[12];
    float* out = (float*)d_out;

    char* ws = (char*)d_ws;
    size_t off = 0;
    auto alloc = [&](size_t bytes) {
        void* p = ws + off;
        off = (off + bytes + 255) & ~(size_t)255;
        return p;
    };
    int*            hist      = (int*)alloc(NODES_TOT * 4);
    int*            row_start = (int*)alloc(NODES_TOT * 4);
    int*            cursor    = (int*)alloc(NODES_TOT * 4);
    int*            csr_src   = (int*)alloc((size_t)EDGES * 4);
    float*          h1        = (float*)alloc((size_t)NODES_TOT * 64 * 4);
    unsigned short* A1        = (unsigned short*)alloc((size_t)NODES_TOT * 64 * 2);
    float*          Cp1       = (float*)alloc((size_t)KSPLIT * BATCH * N1 * 4);
    unsigned short* A2        = (unsigned short*)alloc((size_t)BATCH * N1 * 2);
    float*          Cp2       = (float*)alloc((size_t)KSPLIT * BATCH * N2 * 4);
    float*          C2        = (float*)alloc((size_t)BATCH * N2 * 4);

    const int* src = edge;
    const int* dst = edge + EDGES;

    zero_kernel<<<(NODES_TOT + 255) / 256, 256, 0, stream>>>(hist, NODES_TOT);
    hist_kernel<<<(EDGES + 255) / 256, 256, 0, stream>>>(dst, hist);
    scan_kernel<<<1, 1024, 0, stream>>>(hist, row_start, cursor);
    csr_fill_kernel<<<(EDGES + 255) / 256, 256, 0, stream>>>(src, dst, cursor, csr_src);

    conv_kernel<false><<<928, 256, 0, stream>>>(z, csr_src, row_start, hist, w1_l, b1_l, w1_r, h1);
    conv_kernel<true><<<928, 256, 0, stream>>>(h1, csr_src, row_start, hist, w2_l, b2_l, w2_r, A1);

    // FC1: 116 n-tiles x 4 k-splits (29 sub-steps each)
    gemm_burst<<<dim3(N1 / 64, KSPLIT), 256, 0, stream>>>(A1, fc1_w, Cp1, N1);
    reduce1_kernel<<<(BATCH * N1 / 4 + 255) / 256, 256, 0, stream>>>(Cp1, fc1_b, A2);

    // FC2: 211 n-tiles x 4 k-splits
    gemm_burst<<<dim3((N2 + 63) / 64, KSPLIT), 256, 0, stream>>>(A2, fc2_w, Cp2, N2);
    reduce2_kernel<<<(BATCH * N2 / 4 + 255) / 256, 256, 0, stream>>>(Cp2, fc2_b, C2);

    sym_kernel<<<(BATCH * NN * NN + 255) / 256, 256, 0, stream>>>(C2, out);
}